// Round 4
// baseline (336.599 us; speedup 1.0000x reference)
//
#include <hip/hip_runtime.h>
#include <hip/hip_cooperative_groups.h>
#include <math.h>

namespace cg = cooperative_groups;

// Problem constants (from reference setup_inputs)
#define BATCH 64
#define NPATCH 784
#define DIM 768
#define KSEL 392          // int(784 * 0.5)
#define SIDE 28
#define HWDIM 448
#define NPIX (HWDIM*HWDIM)     // 200704
#define PARTS 49               // partial-reduction tasks per batch for COG
#define PIX_PER_PART (NPIX/PARTS)  // 4096
#define GSPLIT 4               // selection blocks per batch
#define IPB 196                // elements per selection block (784/4)
#define NBLOCKS 1024           // cooperative grid: 4 blocks/CU on 256 CUs

typedef float f4v __attribute__((ext_vector_type(4)));

// ---------------------------------------------------------------------------
// Single cooperative kernel: COG partials -> grid.sync -> selection ->
// grid.sync -> gather+add. Numerics identical to the verified multi-kernel
// version (fixed-order f64 trees; f32 rounding emulation of numpy).
// ---------------------------------------------------------------------------
__global__ __launch_bounds__(256, 4) void fused_all(
        const float* __restrict__ magno,   // [64, 784, 768]
        const float* __restrict__ pos,     // [1, 785, 768]
        const float* __restrict__ scores,  // [64, 784]
        const float* __restrict__ ld,      // [64, 1, 448, 448]
        double* __restrict__ part,         // ws: [64*49*3]
        int* __restrict__ sel,             // ws: [64*392]
        float* __restrict__ out) {         // [64, 392, 768]
    cg::grid_group grid = cg::this_grid();
    const int t = threadIdx.x;
    const int blk = blockIdx.x;

    // ================= Phase 1: COG partial sums =================
    {
        __shared__ double red[3 * 256];
        for (int task = blk; task < BATCH * PARTS; task += NBLOCKS) {
            const int b = task / PARTS;
            const int p = task % PARTS;
            const float* base = ld + (size_t)b * NPIX + (size_t)p * PIX_PER_PART;
            double s = 0.0, sy = 0.0, sx = 0.0;

            // 4096 pixels = 1024 float4; 256 threads x 4 float4 each.
            // 448 % 4 == 0 so each float4 stays within one image row.
            #pragma unroll
            for (int r = 0; r < 4; ++r) {
                const int f4 = r * 256 + t;                 // 0..1023
                const int pix = p * PIX_PER_PART + f4 * 4;  // within-batch pixel idx
                const f4v v = reinterpret_cast<const f4v*>(base)[f4];
                const int i = pix / HWDIM;
                const int j = pix - i * HWDIM;
                // linspace(0,1,448)[i] as numpy computes it: f32(i/447)
                const float yf = (float)((double)i / 447.0);
                const float x0 = (float)((double)(j + 0) / 447.0);
                const float x1 = (float)((double)(j + 1) / 447.0);
                const float x2 = (float)((double)(j + 2) / 447.0);
                const float x3 = (float)((double)(j + 3) / 447.0);
                s  += (double)v.x + (double)v.y + (double)v.z + (double)v.w;
                sy += (double)__fmul_rn(v.x, yf) + (double)__fmul_rn(v.y, yf)
                    + (double)__fmul_rn(v.z, yf) + (double)__fmul_rn(v.w, yf);
                sx += (double)__fmul_rn(v.x, x0) + (double)__fmul_rn(v.y, x1)
                    + (double)__fmul_rn(v.z, x2) + (double)__fmul_rn(v.w, x3);
            }

            __syncthreads();   // red[] safe to overwrite (prev task done)
            red[t] = s; red[256 + t] = sy; red[512 + t] = sx;
            __syncthreads();
            for (int off = 128; off > 0; off >>= 1) {
                if (t < off) {
                    red[t]       += red[t + off];
                    red[256 + t] += red[256 + t + off];
                    red[512 + t] += red[512 + t + off];
                }
                __syncthreads();
            }
            if (t == 0) {
                double* dst = part + (size_t)task * 3;
                dst[0] = red[0]; dst[1] = red[256]; dst[2] = red[512];
            }
        }
    }
    grid.sync();

    // ================= Phase 2: selection (blocks 0..255) =================
    if (blk < BATCH * GSPLIT) {
        const int b = blk / GSPLIT;
        const int g = blk % GSPLIT;

        __shared__ alignas(16) float sw[NPATCH];
        __shared__ double sd[3][64];
        __shared__ float scog[2];
        __shared__ int redc[256];

        // COG combine (deterministic fixed-order tree over 49 partials;
        // identical code+data in all 4 blocks of a batch -> identical result)
        if (t < 64) {
            if (t < PARTS) {
                const double* src = part + (size_t)(b * PARTS + t) * 3;
                sd[0][t] = src[0]; sd[1][t] = src[1]; sd[2][t] = src[2];
            } else {
                sd[0][t] = 0.0; sd[1][t] = 0.0; sd[2][t] = 0.0;
            }
        }
        __syncthreads();
        for (int off = 32; off > 0; off >>= 1) {
            if (t < off) {
                sd[0][t] += sd[0][t + off];
                sd[1][t] += sd[1][t + off];
                sd[2][t] += sd[2][t + off];
            }
            __syncthreads();
        }
        if (t == 0) {
            // reference: total = sum + 1e-6 (f32); cog = num / total (f32)
            const float total = __fadd_rn((float)sd[0][0], 1e-6f);
            scog[0] = __fdiv_rn((float)sd[1][0], total);   // cy
            scog[1] = __fdiv_rn((float)sd[2][0], total);   // cx
        }
        __syncthreads();
        const float cy = scog[0];
        const float cx = scog[1];

        // weighted scores
        int local_above = 0;
        for (int n = t; n < NPATCH; n += 256) {
            const int r = n / SIDE;
            const int c = n - r * SIDE;
            // linspace(0,1,28)[i] = f32(i/27)
            const float gy = (float)((double)r / 27.0);
            const float gx = (float)((double)c / 27.0);
            const float dy = gy - cy;
            const float dx = gx - cx;
            // numpy: dy2, dx2 rounded separately, then summed (no FMA)
            const float dy2 = __fmul_rn(dy, dy);
            const float dx2 = __fmul_rn(dx, dx);
            const float d2 = __fadd_rn(dy2, dx2);
            // -d2/0.125 == -8*d2 exactly; exp in f64 then round (<=0.5 ulp)
            const float w = (float)exp((double)(-8.0f * d2));
            const float wt = __fmul_rn(scores[(size_t)b * NPATCH + n], w);
            sw[n] = wt;
            local_above += (wt > 0.3f) ? 1 : 0;
        }

        redc[t] = local_above;
        __syncthreads();
        for (int off = 128; off > 0; off >>= 1) {
            if (t < off) redc[t] += redc[t + off];
            __syncthreads();
        }
        const int count = redc[0];
        const bool use_topk = (count == 0) || (count >= KSEL);

        // stable rank via float4 LDS broadcast reads; exactly reproduces
        // lax.top_k tie-break (rank = #{w>wi} + #{j<i: w==wi}) and the
        // (ascending-above, then masked-top-k) combined path
        const int i = g * IPB + t;
        if (t < IPB) {
            const float wi = sw[i];
            const bool above_i = wi > 0.3f;
            int r_all = 0, r_below = 0, r_pre = 0;
            const f4v* swv = reinterpret_cast<const f4v*>(sw);
            #pragma unroll 4
            for (int j4 = 0; j4 < NPATCH / 4; ++j4) {
                const f4v w4 = swv[j4];
                const int jb = j4 * 4;
                {
                    const bool gt = (w4.x > wi) || ((w4.x == wi) && (jb + 0 < i));
                    const bool aj = w4.x > 0.3f;
                    r_all += gt; r_below += gt && !aj; r_pre += aj && (jb + 0 < i);
                }
                {
                    const bool gt = (w4.y > wi) || ((w4.y == wi) && (jb + 1 < i));
                    const bool aj = w4.y > 0.3f;
                    r_all += gt; r_below += gt && !aj; r_pre += aj && (jb + 1 < i);
                }
                {
                    const bool gt = (w4.z > wi) || ((w4.z == wi) && (jb + 2 < i));
                    const bool aj = w4.z > 0.3f;
                    r_all += gt; r_below += gt && !aj; r_pre += aj && (jb + 2 < i);
                }
                {
                    const bool gt = (w4.w > wi) || ((w4.w == wi) && (jb + 3 < i));
                    const bool aj = w4.w > 0.3f;
                    r_all += gt; r_below += gt && !aj; r_pre += aj && (jb + 3 < i);
                }
            }
            int* selb = sel + (size_t)b * KSEL;
            if (use_topk) {
                if (r_all < KSEL) selb[r_all] = i;        // stable descending top-k
            } else if (above_i) {
                selb[r_pre] = i;                          // ascending above indices
            } else {
                const int pos = count + r_below;          // masked top-k remainder
                if (pos < KSEL) selb[pos] = i;
            }
        }
    }
    grid.sync();

    // ================= Phase 3: gather + add =================
    {
        const int wid = t >> 6;
        const int lane = t & 63;
        for (int row = blk * 4 + wid; row < BATCH * KSEL; row += NBLOCKS * 4) {
            const int b = row / KSEL;
            const int s = sel[row];
            const f4v* src = reinterpret_cast<const f4v*>(magno + ((size_t)b * NPATCH + s) * DIM);
            const f4v* pp  = reinterpret_cast<const f4v*>(pos + (size_t)(s + 1) * DIM);
            f4v* dst = reinterpret_cast<f4v*>(out + (size_t)row * DIM);
            #pragma unroll
            for (int r = 0; r < 3; ++r) {
                const int c = r * 64 + lane;
                dst[c] = src[c] + pp[c];
            }
        }
    }
}

extern "C" void kernel_launch(void* const* d_in, const int* in_sizes, int n_in,
                              void* d_out, int out_size, void* d_ws, size_t ws_size,
                              hipStream_t stream) {
    const float* magno  = (const float*)d_in[0];  // [64, 784, 768]
    const float* vit    = (const float*)d_in[1];  // [1, 785, 768]
    const float* scores = (const float*)d_in[2];  // [64, 784]
    const float* ld     = (const float*)d_in[3];  // [64, 1, 448, 448]
    float* out = (float*)d_out;                   // [64, 392, 768]

    // workspace layout
    double* partials = (double*)d_ws;             // 64*49*3 doubles
    int*    sel = (int*)((char*)d_ws + (size_t)BATCH * PARTS * 3 * sizeof(double));

    void* args[] = {(void*)&magno, (void*)&vit, (void*)&scores, (void*)&ld,
                    (void*)&partials, (void*)&sel, (void*)&out};
    hipLaunchCooperativeKernel((const void*)fused_all, dim3(NBLOCKS), dim3(256),
                               args, 0, stream);
}

// Round 5
// 54.110 us; speedup vs baseline: 6.2206x; 6.2206x over previous
//
#include <hip/hip_runtime.h>
#include <math.h>

// Problem constants (from reference setup_inputs)
#define BATCH 64
#define NPATCH 784
#define DIM 768
#define KSEL 392          // int(784 * 0.5)
#define SIDE 28
#define HWDIM 448
#define NPIX (HWDIM*HWDIM)     // 200704
#define PARTS 49               // blocks per batch for COG partial reduction
#define PIX_PER_PART (NPIX/PARTS)  // 4096
#define GSPLIT 4               // selection blocks per batch
#define IPB 196                // elements per selection block (784/4)

typedef float f4v __attribute__((ext_vector_type(4)));
typedef unsigned long long u64;

// ---------------------------------------------------------------------------
// Kernel 1: partial COG sums per (batch, part). Deterministic fixed-order
// double accumulation; per-element f32 products emulate numpy rounding.
// All f64 divisions hoisted into a 448-entry LDS linspace table.
// ---------------------------------------------------------------------------
__global__ __launch_bounds__(256) void cog_partial(const float* __restrict__ ld,
                                                   double* __restrict__ part) {
    const int blk = blockIdx.x;
    const int b = blk / PARTS;
    const int p = blk % PARTS;
    const int t = threadIdx.x;

    __shared__ alignas(16) float lin[HWDIM];   // f32(e/447.0) == np.linspace(0,1,448)
    for (int e = t; e < HWDIM; e += 256) lin[e] = (float)((double)e / 447.0);
    __syncthreads();

    const float* base = ld + (size_t)b * NPIX + (size_t)p * PIX_PER_PART;
    double s = 0.0, sy = 0.0, sx = 0.0;

    // 4096 pixels per part = 1024 float4; 256 threads x 4 float4 each.
    // 448 % 4 == 0 so each float4 stays within one image row, and j % 4 == 0
    // so the x-coordinate quad is one aligned LDS float4 read.
    #pragma unroll
    for (int r = 0; r < 4; ++r) {
        const int f4 = r * 256 + t;                 // 0..1023
        const int pix = p * PIX_PER_PART + f4 * 4;  // within-batch pixel idx
        const f4v v = reinterpret_cast<const f4v*>(base)[f4];
        const int i = pix / HWDIM;
        const int j = pix - i * HWDIM;
        const float yf = lin[i];
        const f4v xq = *reinterpret_cast<const f4v*>(&lin[j]);
        s  += (double)v.x + (double)v.y + (double)v.z + (double)v.w;
        sy += (double)__fmul_rn(v.x, yf) + (double)__fmul_rn(v.y, yf)
            + (double)__fmul_rn(v.z, yf) + (double)__fmul_rn(v.w, yf);
        sx += (double)__fmul_rn(v.x, xq.x) + (double)__fmul_rn(v.y, xq.y)
            + (double)__fmul_rn(v.z, xq.z) + (double)__fmul_rn(v.w, xq.w);
    }

    __shared__ double red[3 * 256];
    red[t] = s; red[256 + t] = sy; red[512 + t] = sx;
    __syncthreads();
    for (int off = 128; off > 0; off >>= 1) {
        if (t < off) {
            red[t]       += red[t + off];
            red[256 + t] += red[256 + t + off];
            red[512 + t] += red[512 + t + off];
        }
        __syncthreads();
    }
    if (t == 0) {
        double* dst = part + (size_t)(b * PARTS + p) * 3;
        dst[0] = red[0]; dst[1] = red[256]; dst[2] = red[512];
    }
}

// ---------------------------------------------------------------------------
// Kernel 2: fused COG-combine + selection via packed 64-bit sort keys.
//   key(n) = (bits(w_n) << 10) | (1023 - n)   (w_n >= 0, so bit order == value
//   order; low bits break ties exactly like lax.top_k: lower index ranks first)
// Facts used (proven from the reference semantics):
//   - r_all = #{j: key_j > key_i} is the stable descending-top-k slot.
//   - In the combined (0 < count < k) path, a BELOW-threshold element's slot
//     is count + r_below == r_all (every above-threshold j outranks every
//     below-threshold i, strictly).
//   - An ABOVE-threshold element's slot is r_pre = #{above j < i}: a prefix
//     popcount over the 784-bit above-mask (built with wave ballots).
// ---------------------------------------------------------------------------
__global__ __launch_bounds__(256) void select_k(const float* __restrict__ scores,
                                                const double* __restrict__ part,
                                                int* __restrict__ sel) {
    const int blk = blockIdx.x;
    const int b = blk / GSPLIT;
    const int g = blk % GSPLIT;
    const int t = threadIdx.x;
    const int wid = t >> 6;
    const int lane = t & 63;

    __shared__ double sd[3][64];
    __shared__ float scog[2];
    __shared__ alignas(16) u64 skey[NPATCH];
    __shared__ u64 ajm[16];                 // 784-bit above-threshold mask (padded)

    // --- COG combine (deterministic fixed-order tree over 49 partials;
    //     identical code+data in all 4 blocks of a batch) ---
    if (t < 64) {
        if (t < PARTS) {
            const double* src = part + (size_t)(b * PARTS + t) * 3;
            sd[0][t] = src[0]; sd[1][t] = src[1]; sd[2][t] = src[2];
        } else {
            sd[0][t] = 0.0; sd[1][t] = 0.0; sd[2][t] = 0.0;
        }
    }
    __syncthreads();
    for (int off = 32; off > 0; off >>= 1) {
        if (t < off) {
            sd[0][t] += sd[0][t + off];
            sd[1][t] += sd[1][t + off];
            sd[2][t] += sd[2][t + off];
        }
        __syncthreads();
    }
    if (t == 0) {
        // reference: total = sum + 1e-6 (f32); cog = num / total (f32)
        const float total = __fadd_rn((float)sd[0][0], 1e-6f);
        scog[0] = __fdiv_rn((float)sd[1][0], total);   // cy
        scog[1] = __fdiv_rn((float)sd[2][0], total);   // cx
    }
    __syncthreads();
    const float cy = scog[0];
    const float cx = scog[1];

    // --- weighted scores -> keys + ballot above-mask ---
    #pragma unroll
    for (int pass = 0; pass < 4; ++pass) {
        const int n = pass * 256 + t;
        const bool valid = n < NPATCH;
        float wt = 0.0f;
        if (valid) {
            const int r = n / SIDE;
            const int c = n - r * SIDE;
            // linspace(0,1,28)[i] = f32(i/27)
            const float gy = (float)((double)r / 27.0);
            const float gx = (float)((double)c / 27.0);
            const float dy = gy - cy;
            const float dx = gx - cx;
            // numpy: dy2, dx2 rounded separately, then summed (no FMA)
            const float dy2 = __fmul_rn(dy, dy);
            const float dx2 = __fmul_rn(dx, dx);
            const float d2 = __fadd_rn(dy2, dx2);
            // -d2/0.125 == -8*d2 exactly; exp in f64 then round (<=0.5 ulp)
            const float w = (float)exp((double)(-8.0f * d2));
            wt = __fmul_rn(scores[(size_t)b * NPATCH + n], w);
            skey[n] = ((u64)__float_as_uint(wt) << 10) | (u64)(1023 - n);
        }
        const u64 m = __ballot(valid && (wt > 0.3f));
        if (lane == 0) ajm[pass * 4 + wid] = m;     // bits for n in [64q, 64q+64)
    }
    __syncthreads();

    // --- rank my element ---
    const int i = g * IPB + t;
    if (t < IPB) {
        const u64 ki = skey[i];
        int r0 = 0, r1 = 0, r2 = 0, r3 = 0;
        #pragma unroll 4
        for (int j = 0; j < NPATCH; j += 4) {
            r0 += skey[j + 0] > ki;
            r1 += skey[j + 1] > ki;
            r2 += skey[j + 2] > ki;
            r3 += skey[j + 3] > ki;
        }
        const int r_all = (r0 + r1) + (r2 + r3);

        int count = 0;
        #pragma unroll
        for (int q = 0; q < 16; ++q) count += __popcll(ajm[q]);

        const int qi = i >> 6;
        const bool above_i = (ajm[qi] >> (u64)(i & 63)) & 1ull;
        int r_pre = 0;
        for (int q = 0; q < qi; ++q) r_pre += __popcll(ajm[q]);
        r_pre += __popcll(ajm[qi] & ((1ull << (u64)(i & 63)) - 1ull));

        const bool use_topk = (count == 0) || (count >= KSEL);
        const int dst = (!use_topk && above_i) ? r_pre : r_all;
        if (dst < KSEL) sel[(size_t)b * KSEL + dst] = i;
    }
}

// ---------------------------------------------------------------------------
// Kernel 3: gather + add. 256 threads = 4 waves; one row per wave,
// 3 float4 per lane, all loads issued before the adds. Plain (cached) loads.
// ---------------------------------------------------------------------------
__global__ __launch_bounds__(256) void gather_add(const float* __restrict__ magno,
                                                  const float* __restrict__ pos,
                                                  const int* __restrict__ sel,
                                                  float* __restrict__ out) {
    const int wid = threadIdx.x >> 6;
    const int lane = threadIdx.x & 63;
    const int row = blockIdx.x * 4 + wid;   // 0 .. BATCH*KSEL-1
    const int b = row / KSEL;
    const int s = sel[row];

    const f4v* src = reinterpret_cast<const f4v*>(magno + ((size_t)b * NPATCH + s) * DIM);
    const f4v* pp  = reinterpret_cast<const f4v*>(pos + (size_t)(s + 1) * DIM);
    f4v* dst = reinterpret_cast<f4v*>(out + (size_t)row * DIM);

    const f4v a0 = src[lane], a1 = src[64 + lane], a2 = src[128 + lane];
    const f4v p0 = pp[lane],  p1 = pp[64 + lane],  p2 = pp[128 + lane];
    dst[lane]       = a0 + p0;
    dst[64 + lane]  = a1 + p1;
    dst[128 + lane] = a2 + p2;
}

extern "C" void kernel_launch(void* const* d_in, const int* in_sizes, int n_in,
                              void* d_out, int out_size, void* d_ws, size_t ws_size,
                              hipStream_t stream) {
    const float* magno  = (const float*)d_in[0];  // [64, 784, 768]
    const float* vit    = (const float*)d_in[1];  // [1, 785, 768]
    const float* scores = (const float*)d_in[2];  // [64, 784]
    const float* ld     = (const float*)d_in[3];  // [64, 1, 448, 448]
    float* out = (float*)d_out;                   // [64, 392, 768]

    // workspace layout
    double* partials = (double*)d_ws;             // 64*49*3 doubles
    int*    sel = (int*)((char*)d_ws + (size_t)BATCH * PARTS * 3 * sizeof(double));

    cog_partial<<<dim3(BATCH * PARTS), dim3(256), 0, stream>>>(ld, partials);
    select_k<<<dim3(BATCH * GSPLIT), dim3(256), 0, stream>>>(scores, partials, sel);
    gather_add<<<dim3(BATCH * KSEL / 4), dim3(256), 0, stream>>>(magno, vit, sel, out);
}